// Round 10
// baseline (656.047 us; speedup 1.0000x reference)
//
#include <hip/hip_runtime.h>
#include <hip/hip_bf16.h>
#include <hip/hip_cooperative_groups.h>

namespace cg = cooperative_groups;

typedef __attribute__((ext_vector_type(8))) short bf16x8;
typedef __attribute__((ext_vector_type(4))) float f32x4;
typedef __attribute__((ext_vector_type(4), aligned(4))) float f32x4u;
typedef __attribute__((ext_vector_type(2), aligned(4))) float f32x2u;

__device__ __forceinline__ unsigned short f2bf(float f) {
    unsigned int u = __float_as_uint(f);
    unsigned int r = (u + 0x7fffu + ((u >> 16) & 1u)) >> 16;
    return (unsigned short)r;
}
__device__ __forceinline__ float bflo(unsigned int u) { return __uint_as_float(u << 16); }
__device__ __forceinline__ float bfhi(unsigned int u) { return __uint_as_float(u & 0xffff0000u); }

__device__ __forceinline__ bf16x8 load8_bf(const float* p) {
    f32x4u a = *(const f32x4u*)p;
    f32x4u b = *(const f32x4u*)(p + 4);
    bf16x8 r;
    r[0] = f2bf(a[0]); r[1] = f2bf(a[1]); r[2] = f2bf(a[2]); r[3] = f2bf(a[3]);
    r[4] = f2bf(b[0]); r[5] = f2bf(b[1]); r[6] = f2bf(b[2]); r[7] = f2bf(b[3]);
    return r;
}
__device__ __forceinline__ bf16x8 load7z_bf(const float* p) {
    f32x4u a = *(const f32x4u*)p;
    f32x2u b = *(const f32x2u*)(p + 4);
    float c = p[6];
    bf16x8 r;
    r[0] = f2bf(a[0]); r[1] = f2bf(a[1]); r[2] = f2bf(a[2]); r[3] = f2bf(a[3]);
    r[4] = f2bf(b[0]); r[5] = f2bf(b[1]); r[6] = f2bf(c);  r[7] = 0;
    return r;
}

// ====================== FUSED COOPERATIVE KERNEL ======================
// phase 0: out=x (grid-stride) + UV table (blocks 1..) + consts (block 0)
// grid.sync()
// phase 1: grid-stride edge tiles (wave-autonomous, r9 body)
// LDS 18.4 KB, VGPR target <=64 -> 8 blocks/CU = 32 waves/CU.
__global__ __launch_bounds__(256, 8) void fused_kernel(
    const float* __restrict__ x, const float* __restrict__ cond,
    const float* __restrict__ edge_dist,
    const float* __restrict__ ew1, const float* __restrict__ eb1,
    const float* __restrict__ ew2, const float* __restrict__ eb2,
    const float* __restrict__ cw1, const float* __restrict__ cb1,
    const float* __restrict__ cw2,
    const int* __restrict__ edge_index, const int* __restrict__ tptr,
    float* __restrict__ out,
    unsigned short* __restrict__ bt_M, float* __restrict__ c0,
    unsigned short* __restrict__ UV,
    int E, int BN, int n_out)
{
    __shared__ __align__(16) unsigned short smem[128 * 72];   // 18432 B

    const int b = blockIdx.x, tid = threadIdx.x, ngrid = gridDim.x;
    const int lane = tid & 63, wid = tid >> 6;
    const int fr = lane & 15, kq = lane >> 4;

    // ---- phase 0a: out = x ----
    for (int i = b * 256 + tid; i < n_out; i += ngrid * 256)
        out[i] = x[i];

    if (b == 0) {
        // ---- consts: bt_M[col][p], c0[j] ----
        if (tid < 128) {
            int j = tid;
            float t = (float)tptr[0];
            float cacc = cb1[j] + t * (cw1[63 * 128 + j] + cw1[127 * 128 + j]);
            float m[32];
            #pragma unroll
            for (int p = 0; p < 32; ++p) m[p] = 0.f;
            for (int i = 0; i < 32; ++i) {
                float w = cw1[(128 + i) * 128 + j];
                cacc = fmaf(eb2[i], w, cacc);
                #pragma unroll
                for (int p = 0; p < 32; ++p) m[p] = fmaf(ew2[p * 32 + i], w, m[p]);
            }
            c0[j] = cacc;
            #pragma unroll
            for (int p = 0; p < 32; ++p) bt_M[j * 32 + p] = f2bf(m[p]);
        }
    } else {
        // ---- UV for nodes [nbeg, nend), two 128-col passes (h=0:U, h=1:V) ----
        const int nuvb = ngrid - 1;
        const int npb = (BN + nuvb - 1) / nuvb;
        const int nbeg = (b - 1) * npb;
        const int nend = (nbeg + npb < BN) ? (nbeg + npb) : BN;
        if (nbeg < nend) {
            for (int h = 0; h < 2; ++h) {
                {   // build bt2 half: smem[c][k] = W2^T bf16, c in [0,128)
                    const int c = tid >> 1;
                    const float* colp = (h == 0) ? (cw1 + c) : (cw1 + 64 * 128 + c);
                    const int k0 = (tid & 1) * 32;
                    for (int kk = 0; kk < 32; ++kk) {
                        int k = k0 + kk;
                        float v = (k < 63) ? colp[k * 128] : 0.f;
                        smem[c * 72 + k] = f2bf(v);
                    }
                }
                __syncthreads();
                for (int base = nbeg; base < nend; base += 64) {
                    int node = base + wid * 16 + fr;
                    if (node >= nend) node = nend - 1;
                    const float* cp = cond + (long)node * 63;
                    bf16x8 b0 = load8_bf(cp + 8 * kq);
                    bf16x8 b1 = (kq < 3) ? load8_bf(cp + 32 + 8 * kq) : load7z_bf(cp + 56);
                    char* UVb = (char*)UV;
                    unsigned off0 = (unsigned)node * 512u + (unsigned)(h * 256) + (unsigned)(kq * 8);
                    #pragma unroll
                    for (int n = 0; n < 8; ++n) {
                        bf16x8 a0 = *reinterpret_cast<const bf16x8*>(&smem[(n * 16 + fr) * 72 + 8 * kq]);
                        bf16x8 a1 = *reinterpret_cast<const bf16x8*>(&smem[(n * 16 + fr) * 72 + 32 + 8 * kq]);
                        f32x4 acc = (f32x4){0.f, 0.f, 0.f, 0.f};
                        acc = __builtin_amdgcn_mfma_f32_16x16x32_bf16(a0, b0, acc, 0, 0, 0);
                        acc = __builtin_amdgcn_mfma_f32_16x16x32_bf16(a1, b1, acc, 0, 0, 0);
                        uint2 pk;
                        pk.x = (unsigned)f2bf(acc[0]) | ((unsigned)f2bf(acc[1]) << 16);
                        pk.y = (unsigned)f2bf(acc[2]) | ((unsigned)f2bf(acc[3]) << 16);
                        *reinterpret_cast<uint2*>(UVb + off0 + n * 32) = pk;
                    }
                }
                __syncthreads();
            }
        }
    }

    cg::this_grid().sync();

    // ---- phase 1: edge tiles (grid-stride), wave-autonomous ----
    unsigned short (*s_lds)[40] = reinterpret_cast<unsigned short(*)[40]>(smem);   // 10240 B
    int*   idx0   = reinterpret_cast<int*>((char*)smem + 10240);                   // 512 B
    int*   idx1   = reinterpret_cast<int*>((char*)smem + 10752);                   // 512 B
    float* cw_lds = reinterpret_cast<float*>((char*)smem + 11264);                 // 512 B

    const int lp = lane & 31, hf = lane >> 5;
    const int ntiles = (E + 127) / 128;
    const char* UVb = (const char*)UV;

    for (int t = b; t < ntiles; t += ngrid) {
        const int e0w = t * 128 + wid * 32;

        // 1) indices + wave-local exchange
        {
            int e = e0w + lp; if (e >= E) e = E - 1;
            int v = edge_index[hf ? (E + e) : e];
            (hf ? idx1 : idx0)[wid * 32 + lp] = v;
        }
        asm volatile("s_waitcnt lgkmcnt(0)" ::: "memory");
        int srow[2], drow[2];
        #pragma unroll
        for (int m = 0; m < 2; ++m) {
            srow[m] = idx0[wid * 32 + m * 16 + fr];
            drow[m] = idx1[wid * 32 + m * 16 + fr];
        }

        // 2) issue UV gathers early
        uint2 Lu[2][8], Lv[2][8];
        #pragma unroll
        for (int m = 0; m < 2; ++m) {
            unsigned bu = (unsigned)srow[m] * 512u + (unsigned)(kq * 8);
            unsigned bv = (unsigned)drow[m] * 512u + 256u + (unsigned)(kq * 8);
            #pragma unroll
            for (int g = 0; g < 8; ++g) {
                Lu[m][g] = *reinterpret_cast<const uint2*>(UVb + bu + g * 32);
                Lv[m][g] = *reinterpret_cast<const uint2*>(UVb + bv + g * 32);
            }
        }

        // 3) silu (16 outputs per lane-half)
        {
            int eh = lane >> 1, j0 = (lane & 1) * 16;
            int e = e0w + eh; if (e >= E) e = E - 1;
            float dist = edge_dist[e];
            f32x4u wv[4], bb[4];
            #pragma unroll
            for (int i = 0; i < 4; ++i) {
                wv[i] = *reinterpret_cast<const f32x4u*>(ew1 + j0 + 4 * i);
                bb[i] = *reinterpret_cast<const f32x4u*>(eb1 + j0 + 4 * i);
            }
            unsigned pk[8];
            #pragma unroll
            for (int i = 0; i < 8; ++i) {
                float a0 = fmaf(dist, wv[i >> 1][(i & 1) * 2 + 0], bb[i >> 1][(i & 1) * 2 + 0]);
                float a1 = fmaf(dist, wv[i >> 1][(i & 1) * 2 + 1], bb[i >> 1][(i & 1) * 2 + 1]);
                float s0 = a0 / (1.f + __expf(-a0));
                float s1 = a1 / (1.f + __expf(-a1));
                pk[i] = (unsigned)f2bf(s0) | ((unsigned)f2bf(s1) << 16);
            }
            uint4 q0 = make_uint4(pk[0], pk[1], pk[2], pk[3]);
            uint4 q1 = make_uint4(pk[4], pk[5], pk[6], pk[7]);
            *reinterpret_cast<uint4*>(&s_lds[wid * 32 + eh][j0]) = q0;
            *reinterpret_cast<uint4*>(&s_lds[wid * 32 + eh][j0 + 8]) = q1;
        }
        asm volatile("s_waitcnt lgkmcnt(0)" ::: "memory");

        // 4) B-frags
        bf16x8 sb[2];
        #pragma unroll
        for (int m = 0; m < 2; ++m)
            sb[m] = *reinterpret_cast<const bf16x8*>(&s_lds[wid * 32 + m * 16 + fr][8 * kq]);

        // 5) acc = c0 + U + V; MFMA adds s.M; consume silu*cw2
        float psum[2] = {0.f, 0.f};
        #pragma unroll
        for (int nh = 0; nh < 2; ++nh) {
            f32x4 acc[2][4];
            #pragma unroll
            for (int n = 0; n < 4; ++n) {
                const int g = nh * 4 + n;
                f32x4u c = *reinterpret_cast<const f32x4u*>(c0 + g * 16 + kq * 4);
                #pragma unroll
                for (int m = 0; m < 2; ++m) {
                    unsigned u0 = Lu[m][g].x, u1 = Lu[m][g].y;
                    unsigned v0 = Lv[m][g].x, v1 = Lv[m][g].y;
                    acc[m][n] = (f32x4){ c[0] + bflo(u0) + bflo(v0),
                                         c[1] + bfhi(u0) + bfhi(v0),
                                         c[2] + bflo(u1) + bflo(v1),
                                         c[3] + bfhi(u1) + bfhi(v1) };
                }
            }
            #pragma unroll
            for (int n = 0; n < 4; ++n) {
                const int g = nh * 4 + n;
                bf16x8 aw = *reinterpret_cast<const bf16x8*>(&bt_M[(g * 16 + fr) * 32 + 8 * kq]);
                acc[0][n] = __builtin_amdgcn_mfma_f32_16x16x32_bf16(aw, sb[0], acc[0][n], 0, 0, 0);
                acc[1][n] = __builtin_amdgcn_mfma_f32_16x16x32_bf16(aw, sb[1], acc[1][n], 0, 0, 0);
            }
            #pragma unroll
            for (int n = 0; n < 4; ++n) {
                const int g = nh * 4 + n;
                f32x4u w2 = *reinterpret_cast<const f32x4u*>(cw2 + g * 16 + kq * 4);
                #pragma unroll
                for (int m = 0; m < 2; ++m)
                    #pragma unroll
                    for (int r = 0; r < 4; ++r) {
                        float hh = acc[m][n][r];
                        float sil = hh / (1.f + __expf(-hh));
                        psum[m] = fmaf(sil, w2[r], psum[m]);
                    }
            }
        }

        // 6) kq-reduce + epilogue
        #pragma unroll
        for (int m = 0; m < 2; ++m) {
            psum[m] += __shfl_xor(psum[m], 16, 64);
            psum[m] += __shfl_xor(psum[m], 32, 64);
        }
        if (kq == 0) {
            #pragma unroll
            for (int m = 0; m < 2; ++m)
                cw_lds[wid * 32 + m * 16 + fr] = psum[m];
        }
        asm volatile("s_waitcnt lgkmcnt(0)" ::: "memory");
        if (lane < 32) {
            int e = e0w + lp;
            if (e < E) {
                float coord_w = cw_lds[wid * 32 + lp];
                int src = idx0[wid * 32 + lp];
                int dst = idx1[wid * 32 + lp];
                float dx = x[src * 3 + 0] - x[dst * 3 + 0];
                float dy = x[src * 3 + 1] - x[dst * 3 + 1];
                float dz = x[src * 3 + 2] - x[dst * 3 + 2];
                float len = sqrtf(fmaf(dx, dx, fmaf(dy, dy, dz * dz)));
                len = fmaxf(len, 1e-8f);
                float sc = coord_w / len;
                atomicAdd(&out[dst * 3 + 0], sc * dx);
                atomicAdd(&out[dst * 3 + 1], sc * dy);
                atomicAdd(&out[dst * 3 + 2], sc * dz);
            }
        }
    }
}

// ====================== FALLBACK (r9 two-launch path) ======================
__global__ __launch_bounds__(256) void prep_kernel(
    const float* __restrict__ x, float* __restrict__ out, int n_out,
    const float* __restrict__ cond, const float* __restrict__ cw1,
    const float* __restrict__ ew2, const float* __restrict__ eb2,
    const float* __restrict__ cb1, const int* __restrict__ tptr,
    unsigned short* __restrict__ bt_M, float* __restrict__ c0,
    unsigned short* __restrict__ UV, int BN, int nb_uv)
{
    const int b = blockIdx.x, tid = threadIdx.x;
    if (b < nb_uv) {
        __shared__ __align__(16) unsigned short bt2[256 * 72];
        {
            const int c = tid;
            const float* colp = (c < 128) ? (cw1 + c) : (cw1 + 64 * 128 + (c - 128));
            for (int k = 0; k < 63; ++k)
                bt2[c * 72 + k] = f2bf(colp[k * 128]);
            bt2[c * 72 + 63] = 0;
        }
        __syncthreads();
        const int lane = tid & 63, wid = tid >> 6;
        const int fr = lane & 15, kq = lane >> 4;
        int node = b * 64 + wid * 16 + fr;
        if (node >= BN) node = BN - 1;
        const float* cp = cond + (long)node * 63;
        bf16x8 b0 = load8_bf(cp + 8 * kq);
        bf16x8 b1 = (kq < 3) ? load8_bf(cp + 32 + 8 * kq) : load7z_bf(cp + 56);
        char* UVb = (char*)UV;
        const unsigned off0 = (unsigned)node * 512u + (unsigned)(kq * 8);
        #pragma unroll
        for (int n = 0; n < 16; ++n) {
            bf16x8 a0 = *reinterpret_cast<const bf16x8*>(&bt2[(n * 16 + fr) * 72 + 8 * kq]);
            bf16x8 a1 = *reinterpret_cast<const bf16x8*>(&bt2[(n * 16 + fr) * 72 + 32 + 8 * kq]);
            f32x4 acc = (f32x4){0.f, 0.f, 0.f, 0.f};
            acc = __builtin_amdgcn_mfma_f32_16x16x32_bf16(a0, b0, acc, 0, 0, 0);
            acc = __builtin_amdgcn_mfma_f32_16x16x32_bf16(a1, b1, acc, 0, 0, 0);
            uint2 pk;
            pk.x = (unsigned)f2bf(acc[0]) | ((unsigned)f2bf(acc[1]) << 16);
            pk.y = (unsigned)f2bf(acc[2]) | ((unsigned)f2bf(acc[3]) << 16);
            *reinterpret_cast<uint2*>(UVb + off0 + n * 32) = pk;
        }
    } else if (b == nb_uv) {
        if (tid < 128) {
            int j = tid;
            float t = (float)tptr[0];
            float cacc = cb1[j] + t * (cw1[63 * 128 + j] + cw1[127 * 128 + j]);
            float m[32];
            #pragma unroll
            for (int p = 0; p < 32; ++p) m[p] = 0.f;
            for (int i = 0; i < 32; ++i) {
                float w = cw1[(128 + i) * 128 + j];
                cacc = fmaf(eb2[i], w, cacc);
                #pragma unroll
                for (int p = 0; p < 32; ++p) m[p] = fmaf(ew2[p * 32 + i], w, m[p]);
            }
            c0[j] = cacc;
            #pragma unroll
            for (int p = 0; p < 32; ++p) bt_M[j * 32 + p] = f2bf(m[p]);
        }
    } else {
        int i = (b - nb_uv - 1) * 256 + tid;
        if (i < n_out) out[i] = x[i];
    }
}

__global__ __launch_bounds__(256, 4) void edge_kernel(
    const float* __restrict__ x, const float* __restrict__ edge_dist,
    const float* __restrict__ ew1, const float* __restrict__ eb1,
    const unsigned short* __restrict__ bt_M, const float* __restrict__ c0f,
    const float* __restrict__ cw2, const unsigned short* __restrict__ UV,
    const int* __restrict__ edge_index, float* __restrict__ out, int E)
{
    __shared__ __align__(16) unsigned short s_lds[128][40];
    __shared__ int idx_lds[2][128];
    __shared__ float cw_lds[128];

    const int tid = threadIdx.x, lane = tid & 63, wid = tid >> 6;
    const int fr = lane & 15, kq = lane >> 4;
    const int lp = lane & 31, hf = lane >> 5;
    const int e0w = blockIdx.x * 128 + wid * 32;

    {
        int e = e0w + lp; if (e >= E) e = E - 1;
        idx_lds[hf][wid * 32 + lp] = edge_index[hf ? (E + e) : e];
    }
    asm volatile("s_waitcnt lgkmcnt(0)" ::: "memory");
    int srow[2], drow[2];
    #pragma unroll
    for (int m = 0; m < 2; ++m) {
        srow[m] = idx_lds[0][wid * 32 + m * 16 + fr];
        drow[m] = idx_lds[1][wid * 32 + m * 16 + fr];
    }
    const char* UVb = (const char*)UV;
    uint2 Lu[2][8], Lv[2][8];
    #pragma unroll
    for (int m = 0; m < 2; ++m) {
        unsigned bu = (unsigned)srow[m] * 512u + (unsigned)(kq * 8);
        unsigned bv = (unsigned)drow[m] * 512u + 256u + (unsigned)(kq * 8);
        #pragma unroll
        for (int g = 0; g < 8; ++g) {
            Lu[m][g] = *reinterpret_cast<const uint2*>(UVb + bu + g * 32);
            Lv[m][g] = *reinterpret_cast<const uint2*>(UVb + bv + g * 32);
        }
    }
    {
        int eh = lane >> 1, j0 = (lane & 1) * 16;
        int e = e0w + eh; if (e >= E) e = E - 1;
        float dist = edge_dist[e];
        f32x4u wv[4], bb[4];
        #pragma unroll
        for (int i = 0; i < 4; ++i) {
            wv[i] = *reinterpret_cast<const f32x4u*>(ew1 + j0 + 4 * i);
            bb[i] = *reinterpret_cast<const f32x4u*>(eb1 + j0 + 4 * i);
        }
        unsigned pk[8];
        #pragma unroll
        for (int i = 0; i < 8; ++i) {
            float a0 = fmaf(dist, wv[i >> 1][(i & 1) * 2 + 0], bb[i >> 1][(i & 1) * 2 + 0]);
            float a1 = fmaf(dist, wv[i >> 1][(i & 1) * 2 + 1], bb[i >> 1][(i & 1) * 2 + 1]);
            float s0 = a0 / (1.f + __expf(-a0));
            float s1 = a1 / (1.f + __expf(-a1));
            pk[i] = (unsigned)f2bf(s0) | ((unsigned)f2bf(s1) << 16);
        }
        uint4 q0 = make_uint4(pk[0], pk[1], pk[2], pk[3]);
        uint4 q1 = make_uint4(pk[4], pk[5], pk[6], pk[7]);
        *reinterpret_cast<uint4*>(&s_lds[wid * 32 + eh][j0]) = q0;
        *reinterpret_cast<uint4*>(&s_lds[wid * 32 + eh][j0 + 8]) = q1;
    }
    asm volatile("s_waitcnt lgkmcnt(0)" ::: "memory");
    bf16x8 sb[2];
    #pragma unroll
    for (int m = 0; m < 2; ++m)
        sb[m] = *reinterpret_cast<const bf16x8*>(&s_lds[wid * 32 + m * 16 + fr][8 * kq]);
    float psum[2] = {0.f, 0.f};
    #pragma unroll
    for (int nh = 0; nh < 2; ++nh) {
        f32x4 acc[2][4];
        #pragma unroll
        for (int n = 0; n < 4; ++n) {
            const int g = nh * 4 + n;
            f32x4u c = *reinterpret_cast<const f32x4u*>(c0f + g * 16 + kq * 4);
            #pragma unroll
            for (int m = 0; m < 2; ++m) {
                unsigned u0 = Lu[m][g].x, u1 = Lu[m][g].y;
                unsigned v0 = Lv[m][g].x, v1 = Lv[m][g].y;
                acc[m][n] = (f32x4){ c[0] + bflo(u0) + bflo(v0),
                                     c[1] + bfhi(u0) + bfhi(v0),
                                     c[2] + bflo(u1) + bflo(v1),
                                     c[3] + bfhi(u1) + bfhi(v1) };
            }
        }
        #pragma unroll
        for (int n = 0; n < 4; ++n) {
            const int g = nh * 4 + n;
            bf16x8 aw = *reinterpret_cast<const bf16x8*>(&bt_M[(g * 16 + fr) * 32 + 8 * kq]);
            acc[0][n] = __builtin_amdgcn_mfma_f32_16x16x32_bf16(aw, sb[0], acc[0][n], 0, 0, 0);
            acc[1][n] = __builtin_amdgcn_mfma_f32_16x16x32_bf16(aw, sb[1], acc[1][n], 0, 0, 0);
        }
        #pragma unroll
        for (int n = 0; n < 4; ++n) {
            const int g = nh * 4 + n;
            f32x4u w2 = *reinterpret_cast<const f32x4u*>(cw2 + g * 16 + kq * 4);
            #pragma unroll
            for (int m = 0; m < 2; ++m)
                #pragma unroll
                for (int r = 0; r < 4; ++r) {
                    float h = acc[m][n][r];
                    float sil = h / (1.f + __expf(-h));
                    psum[m] = fmaf(sil, w2[r], psum[m]);
                }
        }
    }
    #pragma unroll
    for (int m = 0; m < 2; ++m) {
        psum[m] += __shfl_xor(psum[m], 16, 64);
        psum[m] += __shfl_xor(psum[m], 32, 64);
    }
    if (kq == 0) {
        #pragma unroll
        for (int m = 0; m < 2; ++m)
            cw_lds[wid * 32 + m * 16 + fr] = psum[m];
    }
    asm volatile("s_waitcnt lgkmcnt(0)" ::: "memory");
    if (lane < 32) {
        int e = e0w + lp;
        if (e < E) {
            float coord_w = cw_lds[wid * 32 + lp];
            int src = idx_lds[0][wid * 32 + lp];
            int dst = idx_lds[1][wid * 32 + lp];
            float dx = x[src * 3 + 0] - x[dst * 3 + 0];
            float dy = x[src * 3 + 1] - x[dst * 3 + 1];
            float dz = x[src * 3 + 2] - x[dst * 3 + 2];
            float len = sqrtf(fmaf(dx, dx, fmaf(dy, dy, dz * dz)));
            len = fmaxf(len, 1e-8f);
            float sc = coord_w / len;
            atomicAdd(&out[dst * 3 + 0], sc * dx);
            atomicAdd(&out[dst * 3 + 1], sc * dy);
            atomicAdd(&out[dst * 3 + 2], sc * dz);
        }
    }
}

extern "C" void kernel_launch(void* const* d_in, const int* in_sizes, int n_in,
                              void* d_out, int out_size, void* d_ws, size_t ws_size,
                              hipStream_t stream) {
    const float* x         = (const float*)d_in[0];
    const float* cond      = (const float*)d_in[1];
    const float* edge_dist = (const float*)d_in[2];
    const float* ew1       = (const float*)d_in[3];
    const float* eb1       = (const float*)d_in[4];
    const float* ew2       = (const float*)d_in[5];
    const float* eb2       = (const float*)d_in[6];
    // d_in[7..10] = node_mlp weights: dead code (h_out discarded by reference)
    const float* cw1       = (const float*)d_in[11];
    const float* cb1       = (const float*)d_in[12];
    const float* cw2       = (const float*)d_in[13];
    const int*   edge_index= (const int*)d_in[14];
    const int*   tptr      = (const int*)d_in[15];
    float* out = (float*)d_out;

    const int E  = in_sizes[2];        // 800000
    const int BN = in_sizes[1] / 63;   // 50000
    const int n_out = out_size;        // 150000

    char* ws = (char*)d_ws;
    unsigned short* bt_M = (unsigned short*)(ws);            // 8 KB
    float*          c0   = (float*)(ws + 8192);              // 512 B
    unsigned short* UV   = (unsigned short*)(ws + 65536);    // BN*256*2 = 25.6 MB

    // co-resident grid for cooperative launch
    int nb_per_cu = 0;
    hipError_t qe = hipOccupancyMaxActiveBlocksPerMultiprocessor(
        &nb_per_cu, (const void*)fused_kernel, 256, 0);
    if (qe != hipSuccess || nb_per_cu < 1) nb_per_cu = 1;
    int grid = nb_per_cu * 256;               // 256 CUs on MI355X
    if (grid > 4096) grid = 4096;

    void* args[] = {
        (void*)&x, (void*)&cond, (void*)&edge_dist,
        (void*)&ew1, (void*)&eb1, (void*)&ew2, (void*)&eb2,
        (void*)&cw1, (void*)&cb1, (void*)&cw2,
        (void*)&edge_index, (void*)&tptr, (void*)&out,
        (void*)&bt_M, (void*)&c0, (void*)&UV,
        (void*)&E, (void*)&BN, (void*)&n_out
    };
    hipError_t le = hipLaunchCooperativeKernel(
        (const void*)fused_kernel, dim3(grid), dim3(256), args, 0, stream);

    if (le != hipSuccess) {
        // fallback: r9 two-launch path
        const int nb_uv = (BN + 63) / 64;
        const int nb_out = (n_out + 255) / 256;
        prep_kernel<<<nb_uv + 1 + nb_out, 256, 0, stream>>>(
            x, out, n_out, cond, cw1, ew2, eb2, cb1, tptr, bt_M, c0, UV, BN, nb_uv);
        int blocks = (E + 127) / 128;
        edge_kernel<<<blocks, 256, 0, stream>>>(x, edge_dist, ew1, eb1,
                                                bt_M, c0, cw2, UV,
                                                edge_index, out, E);
    }
}